// Round 4
// baseline (253.907 us; speedup 1.0000x reference)
//
#include <hip/hip_runtime.h>
#include <stdint.h>
#include <math.h>

#define JAX_PARTITIONABLE 1

#define NB 8
#define NM 144
#define NM16 16
#define NPTS 500
#define GP 16   // floats per pixel record: 10 Gram + 4 u-taps + 2 pad = one 64B line

// ---------------- Threefry-2x32 (JAX-exact) ----------------
__host__ __device__ __forceinline__ uint32_t rotl32(uint32_t x, int r) {
    return (x << r) | (x >> (32 - r));
}

__host__ __device__ inline void threefry2x32(uint32_t k0, uint32_t k1,
                                             uint32_t x0, uint32_t x1,
                                             uint32_t& o0, uint32_t& o1) {
    uint32_t ks2 = k0 ^ k1 ^ 0x1BD11BDAu;
    x0 += k0; x1 += k1;
    const int RA[4] = {13, 15, 26, 6};
    const int RB[4] = {17, 29, 16, 24};
#define R4(ROT) { x0 += x1; x1 = rotl32(x1, ROT[0]); x1 ^= x0; \
                  x0 += x1; x1 = rotl32(x1, ROT[1]); x1 ^= x0; \
                  x0 += x1; x1 = rotl32(x1, ROT[2]); x1 ^= x0; \
                  x0 += x1; x1 = rotl32(x1, ROT[3]); x1 ^= x0; }
    R4(RA); x0 += k1;  x1 += ks2 + 1u;
    R4(RB); x0 += ks2; x1 += k0 + 2u;
    R4(RA); x0 += k0;  x1 += k1 + 3u;
    R4(RB); x0 += k1;  x1 += ks2 + 4u;
    R4(RA); x0 += ks2; x1 += k0 + 5u;
#undef R4
    o0 = x0; o1 = x1;
}

// XLA f32 erf_inv (Giles polynomial pair)
__device__ __forceinline__ float erfinv32(float x) {
    float w = -log1pf(-x * x);
    float p;
    if (w < 5.0f) {
        w = w - 2.5f;
        p = 2.81022636e-08f;
        p = fmaf(p, w, 3.43273939e-07f);
        p = fmaf(p, w, -3.5233877e-06f);
        p = fmaf(p, w, -4.39150654e-06f);
        p = fmaf(p, w, 0.00021858087f);
        p = fmaf(p, w, -0.00125372503f);
        p = fmaf(p, w, -0.00417768164f);
        p = fmaf(p, w, 0.246640727f);
        p = fmaf(p, w, 1.50140941f);
    } else {
        w = sqrtf(w) - 3.0f;
        p = -0.000200214257f;
        p = fmaf(p, w, 0.000100950558f);
        p = fmaf(p, w, 0.00134934322f);
        p = fmaf(p, w, -0.00367342844f);
        p = fmaf(p, w, 0.00573950773f);
        p = fmaf(p, w, -0.0076224613f);
        p = fmaf(p, w, 0.00943887047f);
        p = fmaf(p, w, 1.00167406f);
        p = fmaf(p, w, 2.83297682f);
    }
    return p * x;
}

// jax.random.normal element at flat index idx (partitionable: bits = o0^o1).
__device__ __forceinline__ float jax_normal(uint32_t k0, uint32_t k1,
                                            uint32_t idx, uint32_t half) {
    uint32_t o0, o1, bits;
#if JAX_PARTITIONABLE
    threefry2x32(k0, k1, 0u, idx, o0, o1);
    bits = o0 ^ o1;
#else
    if (idx < half) { threefry2x32(k0, k1, idx, idx + half, o0, o1); bits = o0; }
    else            { threefry2x32(k0, k1, idx - half, idx, o0, o1); bits = o1; }
#endif
    uint32_t fb = (bits >> 9) | 0x3F800000u;
    float f = __uint_as_float(fb) - 1.0f;           // [0,1)
    const float lo = -0.99999994f;                  // nextafter(-1,0) f32
    float u = f * (1.0f - lo) + lo;                 // (1.0f - lo) == 2.0f
    u = fmaxf(lo, u);
    return 1.4142135623730951f * erfinv32(u);
}

// ---------------- SE(3) helpers, f32 (evolve path) ----------------
__device__ inline void se3_exp6(const float xi[6], float T[12]) {
    float tx = xi[0], ty = xi[1], tz = xi[2];
    float wx = xi[3], wy = xi[4], wz = xi[5];
    float nrm = sqrtf(wx * wx + wy * wy + wz * wz);
    float theta = fmaxf(nrm, 1e-8f);
    float kx = wx / theta, ky = wy / theta, kz = wz / theta;
    float K[9] = {0.0f, -kz, ky, kz, 0.0f, -kx, -ky, kx, 0.0f};
    float st = sinf(theta);
    float ct = 1.0f - cosf(theta);
    float KK[9];
    for (int i = 0; i < 3; i++)
        for (int j = 0; j < 3; j++)
            KK[i * 3 + j] = K[i * 3 + 0] * K[0 + j] + K[i * 3 + 1] * K[3 + j] + K[i * 3 + 2] * K[6 + j];
    float a = ct / theta;
    float bb = 1.0f - st / theta;
    float R[9], V[9];
    for (int i = 0; i < 3; i++)
        for (int j = 0; j < 3; j++) {
            float e = (i == j) ? 1.0f : 0.0f;
            R[i * 3 + j] = e + st * K[i * 3 + j] + ct * KK[i * 3 + j];
            V[i * 3 + j] = e + a * K[i * 3 + j] + bb * KK[i * 3 + j];
        }
    float t0 = V[0] * tx + V[1] * ty + V[2] * tz;
    float t1 = V[3] * tx + V[4] * ty + V[5] * tz;
    float t2 = V[6] * tx + V[7] * ty + V[8] * tz;
    T[0] = R[0]; T[1] = R[1]; T[2] = R[2];  T[3] = t0;
    T[4] = R[3]; T[5] = R[4]; T[6] = R[5];  T[7] = t1;
    T[8] = R[6]; T[9] = R[7]; T[10] = R[8]; T[11] = t2;
}

__device__ inline void compose44(const float dT[12], const float P[16], float Tn[16]) {
    for (int i = 0; i < 3; i++)
        for (int j = 0; j < 4; j++)
            Tn[i * 4 + j] = dT[i * 4 + 0] * P[0 + j] + dT[i * 4 + 1] * P[4 + j] +
                            dT[i * 4 + 2] * P[8 + j] + dT[i * 4 + 3] * P[12 + j];
    Tn[12] = 0.0f; Tn[13] = 0.0f; Tn[14] = 0.0f; Tn[15] = 1.0f;
}

__device__ inline void make_hypothesis(int m, const float* P, uint32_t hk0, uint32_t hk1,
                                       float Tn[16]) {
    float tn[3];
    for (int c = 0; c < 3; c++)
        tn[c] = jax_normal(hk0, hk1, (uint32_t)(m * 3 + c), 216u);
    int gi = m / 12, gj = m % 12;
    const float d2r = (float)(M_PI / 180.0);
    float xi[6] = {tn[0], tn[1], tn[2], 0.0f,
                   (float)(2 * gi - 11) * d2r, (float)(2 * gj - 11) * d2r};
    float dT[12];
    se3_exp6(xi, dT);
    compose44(dT, P, Tn);
}

// ---------------- SE(3) helpers, f64 (finalize path) ----------------
__device__ inline void se3_exp6d(const double xi[6], double T[12]) {
    double tx = xi[0], ty = xi[1], tz = xi[2];
    double wx = xi[3], wy = xi[4], wz = xi[5];
    double nrm = sqrt(wx * wx + wy * wy + wz * wz);
    double theta = fmax(nrm, 1e-8);
    double kx = wx / theta, ky = wy / theta, kz = wz / theta;
    double K[9] = {0.0, -kz, ky, kz, 0.0, -kx, -ky, kx, 0.0};
    double st = sin(theta);
    double ct = 1.0 - cos(theta);
    double KK[9];
    for (int i = 0; i < 3; i++)
        for (int j = 0; j < 3; j++)
            KK[i * 3 + j] = K[i * 3 + 0] * K[0 + j] + K[i * 3 + 1] * K[3 + j] + K[i * 3 + 2] * K[6 + j];
    double a = ct / theta;
    double bb = 1.0 - st / theta;
    double R[9], V[9];
    for (int i = 0; i < 3; i++)
        for (int j = 0; j < 3; j++) {
            double e = (i == j) ? 1.0 : 0.0;
            R[i * 3 + j] = e + st * K[i * 3 + j] + ct * KK[i * 3 + j];
            V[i * 3 + j] = e + a * K[i * 3 + j] + bb * KK[i * 3 + j];
        }
    double t0 = V[0] * tx + V[1] * ty + V[2] * tz;
    double t1 = V[3] * tx + V[4] * ty + V[5] * tz;
    double t2 = V[6] * tx + V[7] * ty + V[8] * tz;
    T[0] = R[0]; T[1] = R[1]; T[2] = R[2];  T[3] = t0;
    T[4] = R[3]; T[5] = R[4]; T[6] = R[5];  T[7] = t1;
    T[8] = R[6]; T[9] = R[7]; T[10] = R[8]; T[11] = t2;
}

__device__ inline void compose44d(const double dT[12], const double P[16], double Tn[16]) {
    for (int i = 0; i < 3; i++)
        for (int j = 0; j < 4; j++)
            Tn[i * 4 + j] = dT[i * 4 + 0] * P[0 + j] + dT[i * 4 + 1] * P[4 + j] +
                            dT[i * 4 + 2] * P[8 + j] + dT[i * 4 + 3] * P[12 + j];
    Tn[12] = 0.0; Tn[13] = 0.0; Tn[14] = 0.0; Tn[15] = 1.0;
}

__device__ inline void make_hypothesis_d(int m, const double* P, uint32_t hk0, uint32_t hk1,
                                         double Tn[16]) {
    float tn[3];
    for (int c = 0; c < 3; c++)
        tn[c] = jax_normal(hk0, hk1, (uint32_t)(m * 3 + c), 216u);
    int gi = m / 12, gj = m % 12;
    const float d2r = (float)(M_PI / 180.0);
    float pf = (float)(2 * gi - 11) * d2r;
    float yf = (float)(2 * gj - 11) * d2r;
    double xi[6] = {(double)tn[0], (double)tn[1], (double)tn[2], 0.0,
                    (double)pf, (double)yf};
    double dT[12];
    se3_exp6d(xi, dT);
    compose44d(dT, P, Tn);
}

struct IterKeys { uint32_t k0[9]; uint32_t k1[9]; float damping[9]; };

// ---------------- Fused Gram builder, streaming + LDS tiles, T14 order --------
// Block = (batch, 4-row span). Per channel iteration (T14 issue-early order):
//   [issue loads ch j+2 -> regs] [compute from slab[cur]] [barrier: vmcnt drain
//   covered by compute] [ds_write ch j+1 -> slab[cur^1]] [barrier]
// ldA/ldB register double-buffer via unroll-by-2 (no reg copies). x+4 and u
// taps come from __shfl_down(.,1): at all levels every non-row-edge thread's
// neighbor is in the same wave (PT-boundary lanes are always row edges), and
// the shuffled value is the identical subtraction of identical LDS values ->
// bitwise-identical G; kills the stride-4-word bank conflicts of the scalar
// column reads.  fmaf order / channel order / group-sum order g0+g1+... are
// IDENTICAL to previous kernels.
// Record: [M00,M01,M02,M03 | M11,M12,M13,M22 | M23,M33,u00,u01 | u10,u11,0,0]
#define STF 2560   // staged floats per iteration (= 2 * GRP * 5W at all levels)

template <int C, int H, int W, int GRP>
__device__ void gram_body_s(const float* __restrict__ q, const float* __restrict__ r,
                            const float* __restrict__ u, float* __restrict__ G,
                            float* slab, float* part, int blk) {
    constexpr int HW = H * W;
    constexpr int CPG = C / GRP;        // 32 at all levels
    constexpr int R = 4;                // rows per block
    constexpr int PT = 256 / GRP;       // threads per channel-group
    constexpr int SPAN = (R + 1) * W;   // 5W floats per staged array-channel
    constexpr int TPB = H / R;          // row-span tiles per batch
    constexpr int TPR = W / 4;          // threads per row (4 px/thread)
    const int b = blk / TPB;
    const int tile = blk % TPB;
    const int y0 = tile * R;
    const int tid = threadIdx.x;
    const int g = tid / PT;
    const int p = tid % PT;
    const int row_l = p / TPR;
    const int x0 = (p % TPR) * 4;

    // staging decomposition (constant per thread): float2 element k at flat
    // float index f = 2*(tid + 256k) in layout [arr(q,r)][chl(GRP)][5 rows*W]
    const float* ptrk[5];
    int swk[5];
#pragma unroll
    for (int k = 0; k < 5; k++) {
        int f = 2 * (tid + 256 * k);
        swk[k] = f;
        int arr = f / (GRP * SPAN);
        int rem = f - arr * (GRP * SPAN);
        int chl = rem / SPAN;
        int rr  = rem - chl * SPAN;
        int row = rr / W;
        int x   = rr - row * W;
        int gy  = (y0 + row < H) ? (y0 + row) : (H - 1);   // bottom-halo clamp
        const float* base = arr ? r : q;
        ptrk[k] = base + ((size_t)b * C + (size_t)chl * CPG) * HW + (size_t)gy * W + x;
    }

    float acc[4][10];
#pragma unroll
    for (int j = 0; j < 4; j++)
#pragma unroll
        for (int i = 0; i < 10; i++) acc[j][i] = 0.0f;

    const int off0 = row_l * W + x0;
    const int off1 = off0 + W;
    const bool edge = (x0 + 4 >= W);    // row end: x+4 tap clamps to x+3

    float2 ldA[5], ldB[5];
    // prologue: slab0 <- ch0; ldA <- ch1 (in flight across the barrier)
#pragma unroll
    for (int k = 0; k < 5; k++) { ldA[k] = *(const float2*)ptrk[k]; ptrk[k] += HW; }
#pragma unroll
    for (int k = 0; k < 5; k++) *(float2*)&slab[swk[k]] = ldA[k];
#pragma unroll
    for (int k = 0; k < 5; k++) { ldA[k] = *(const float2*)ptrk[k]; ptrk[k] += HW; }
    __syncthreads();

    int cur = 0;
#define GRAM_STEP(JJ, CURLD, NXTLD)                                            \
    {                                                                          \
        if ((JJ) + 2 < CPG) {                                                  \
            _Pragma("unroll")                                                  \
            for (int k = 0; k < 5; k++) {                                      \
                NXTLD[k] = *(const float2*)ptrk[k]; ptrk[k] += HW;             \
            }                                                                  \
        }                                                                      \
        const float* qs = slab + cur * STF + g * SPAN;                         \
        const float* rs = slab + cur * STF + (GRP + g) * SPAN;                 \
        float4 qa = *(const float4*)(qs + off0);                               \
        float4 qb = *(const float4*)(qs + off1);                               \
        float4 ra = *(const float4*)(rs + off0);                               \
        float4 rb = *(const float4*)(rs + off1);                               \
        float e0[5], e1[5];                                                    \
        e0[0] = qa.x - ra.x; e0[1] = qa.y - ra.y;                              \
        e0[2] = qa.z - ra.z; e0[3] = qa.w - ra.w;                              \
        e1[0] = qb.x - rb.x; e1[1] = qb.y - rb.y;                              \
        e1[2] = qb.z - rb.z; e1[3] = qb.w - rb.w;                              \
        float d0n = __shfl_down(e0[0], 1, 64);                                 \
        float d1n = __shfl_down(e1[0], 1, 64);                                 \
        e0[4] = edge ? e0[3] : d0n;                                            \
        e1[4] = edge ? e1[3] : d1n;                                            \
        _Pragma("unroll")                                                      \
        for (int jj = 0; jj < 4; jj++) {                                       \
            float d00 = e0[jj], d01 = e0[jj + 1];                              \
            float d10 = e1[jj], d11 = e1[jj + 1];                              \
            acc[jj][0] = fmaf(d00, d00, acc[jj][0]);                           \
            acc[jj][1] = fmaf(d00, d01, acc[jj][1]);                           \
            acc[jj][2] = fmaf(d00, d10, acc[jj][2]);                           \
            acc[jj][3] = fmaf(d00, d11, acc[jj][3]);                           \
            acc[jj][4] = fmaf(d01, d01, acc[jj][4]);                           \
            acc[jj][5] = fmaf(d01, d10, acc[jj][5]);                           \
            acc[jj][6] = fmaf(d01, d11, acc[jj][6]);                           \
            acc[jj][7] = fmaf(d10, d10, acc[jj][7]);                           \
            acc[jj][8] = fmaf(d10, d11, acc[jj][8]);                           \
            acc[jj][9] = fmaf(d11, d11, acc[jj][9]);                           \
        }                                                                      \
        __syncthreads();                  /* readers of slab[cur] done; */     \
                                          /* vmcnt drain covered by compute */ \
        if ((JJ) + 1 < CPG) {                                                  \
            _Pragma("unroll")                                                  \
            for (int k = 0; k < 5; k++)                                        \
                *(float2*)&slab[(cur ^ 1) * STF + swk[k]] = CURLD[k];          \
        }                                                                      \
        __syncthreads();                  /* slab[cur^1] visible */            \
        cur ^= 1;                                                              \
    }

    for (int j = 0; j < CPG; j += 2) {
        GRAM_STEP(j, ldA, ldB);
        GRAM_STEP(j + 1, ldB, ldA);
    }
#undef GRAM_STEP

    if (GRP > 1) {
        if (g > 0) {
            float* pp = part + (size_t)(g - 1) * 40 * PT;
#pragma unroll
            for (int j = 0; j < 4; j++)
#pragma unroll
                for (int i = 0; i < 10; i++)
                    pp[(j * 10 + i) * PT + p] = acc[j][i];   // stride-1 in p
        }
        __syncthreads();
        if (g == 0) {
            for (int gg = 1; gg < GRP; gg++) {
                const float* pp = part + (size_t)(gg - 1) * 40 * PT;
#pragma unroll
                for (int j = 0; j < 4; j++)
#pragma unroll
                    for (int i = 0; i < 10; i++)
                        acc[j][i] += pp[(j * 10 + i) * PT + p];  // order g0+g1+...
            }
        }
    }

    // stage u's 5-row halo into slab[0..SPAN) (slabs are free now)
#pragma unroll
    for (int k = 0; k < 3; k++) {
        int e2u = tid + 256 * k;
        if (2 * e2u < SPAN) {
            int f = 2 * e2u;
            int row = f / W;
            int x = f - row * W;
            int gy = (y0 + row < H) ? (y0 + row) : (H - 1);
            float2 v = *(const float2*)(u + (size_t)b * HW + (size_t)gy * W + x);
            *(float2*)&slab[f] = v;
        }
    }
    __syncthreads();
    if (g == 0) {   // g==0 is whole waves at all levels -> shfl is wave-uniform
        float w0[5], w1[5];
#pragma unroll
        for (int j = 0; j < 4; j++) {
            w0[j] = slab[off0 + j];
            w1[j] = slab[off1 + j];
        }
        float u0n = __shfl_down(w0[0], 1, 64);
        float u1n = __shfl_down(w1[0], 1, 64);
        w0[4] = edge ? w0[3] : u0n;
        w1[4] = edge ? w1[3] : u1n;
        const int px0 = (y0 + row_l) * W + x0;
#pragma unroll
        for (int j = 0; j < 4; j++) {
            size_t base = ((size_t)b * HW + px0 + j) * GP;
            float4 g0v = {acc[j][0], acc[j][1], acc[j][2], acc[j][3]};
            float4 g1v = {acc[j][4], acc[j][5], acc[j][6], acc[j][7]};
            float4 g2v = {acc[j][8], acc[j][9], w0[j], w0[j + 1]};
            float4 g3v = {w1[j], w1[j + 1], 0.0f, 0.0f};
            *(float4*)(G + base + 0)  = g0v;
            *(float4*)(G + base + 4)  = g1v;
            *(float4*)(G + base + 8)  = g2v;
            *(float4*)(G + base + 12) = g3v;
        }
    }
}

#define SBLK0 96     // L0: 12 row-spans x 8 batches
#define SBLK1 192    // L1: 24 x 8
#define SBLK2 384    // L2: 48 x 8
#define SBLKT (SBLK0 + SBLK1 + SBLK2)   // 672

__global__ __launch_bounds__(256) void gram_fused_kernel(
    const float* __restrict__ q0, const float* __restrict__ r0, const float* __restrict__ u0,
    float* __restrict__ G0,
    const float* __restrict__ q1, const float* __restrict__ r1, const float* __restrict__ u1,
    float* __restrict__ G1,
    const float* __restrict__ q2, const float* __restrict__ r2, const float* __restrict__ u2,
    float* __restrict__ G2) {
    __shared__ float slab[2 * STF];      // 20 KB double-buffered stage
    __shared__ float part[3 * 40 * 64];  // 30 KB group partials (L0 worst)
    const int blk = blockIdx.x;
    if (blk < SBLK0)
        gram_body_s<128, 48, 64, 4>(q0, r0, u0, G0, slab, part, blk);
    else if (blk < SBLK0 + SBLK1)
        gram_body_s<64, 96, 128, 2>(q1, r1, u1, G1, slab, part, blk - SBLK0);
    else
        gram_body_s<32, 192, 256, 1>(q2, r2, u2, G2, slab, part, blk - SBLK0 - SBLK1);
}

// ---------------- Kernel 1 (Gram): per-(b,m) full 9-iteration LM ----------------
// Serial LM tail: one barrier after partial-reduce, wave 0 finishes alone,
// one barrier to publish Tsh. All arithmetic bitwise-identical.
template <int H, int W>
__device__ void run_level_gram(const float* __restrict__ Gb,
                               float fx, float fy, float cx, float cy,
                               const float* geoS, float* Tsh, float* red,
                               const float* nzS, const float* damping,
                               float* out, int b, int m, int firstIter, int niter) {
    const int tid = threadIdx.x;
    for (int it = 0; it < niter; it++) {
        const int iter = firstIter + it;
        float acc = 0.0f;
        if (tid < NPTS) {
            float px = geoS[tid * 3], py = geoS[tid * 3 + 1], pz = geoS[tid * 3 + 2];
            float X = Tsh[0] * px + Tsh[1] * py + Tsh[2]  * pz + Tsh[3];
            float Y = Tsh[4] * px + Tsh[5] * py + Tsh[6]  * pz + Tsh[7];
            float Z = Tsh[8] * px + Tsh[9] * py + Tsh[10] * pz + Tsh[11];
            float z = fmaxf(Z, 1e-6f);
            float uu = fx * (X / z) + cx;
            float vv = fy * (Y / z) + cy;
            float gx = 2.0f * uu / (float)(W - 1) - 1.0f;
            float gy = 2.0f * vv / (float)(H - 1) - 1.0f;
            float x = fminf(fmaxf(((gx + 1.0f) * (float)W - 1.0f) * 0.5f, 0.0f), (float)(W - 1));
            float y = fminf(fmaxf(((gy + 1.0f) * (float)H - 1.0f) * 0.5f, 0.0f), (float)(H - 1));
            float x0f = floorf(x), y0f = floorf(y);
            float wx = x - x0f, wy = y - y0f;
            int x0i = (int)x0f, y0i = (int)y0f;
            int i00 = y0i * W + x0i;
            float w00 = (1.0f - wx) * (1.0f - wy), w01 = wx * (1.0f - wy);
            float w10 = (1.0f - wx) * wy,          w11 = wx * wy;
            const float* Gp = Gb + (size_t)i00 * GP;
            float4 g0 = *(const float4*)(Gp + 0);
            float4 g1 = *(const float4*)(Gp + 4);
            float4 g2 = *(const float4*)(Gp + 8);
            float4 g3 = *(const float4*)(Gp + 12);
            float uval = w00 * g2.z + w01 * g2.w + w10 * g3.x + w11 * g3.y;
            float val = w00 * w00 * g0.x + w01 * w01 * g1.x +
                        w10 * w10 * g1.w + w11 * w11 * g2.y +
                        2.0f * (w00 * w01 * g0.y + w00 * w10 * g0.z + w00 * w11 * g0.w +
                                w01 * w10 * g1.y + w01 * w11 * g1.z + w10 * w11 * g2.x);
            acc = uval * val;
        }
        // per-wave reduction (8 waves) -> red[]
        float v = acc;
        for (int off = 32; off > 0; off >>= 1) v += __shfl_down(v, off, 64);
        if ((tid & 63) == 0) red[tid >> 6] = v;
        __syncthreads();
        if (tid < 64) {   // wave 0 finishes the iteration alone
            float s = 0.0f;
            for (int w = 0; w < 8; w++) s += red[w];   // same serial order
            float res = s / 500.0f;
            if (tid == 0 && iter == 8) out[128 + b * NM + m] = res;
            float st = 0.0f;
            if (tid < 6)
                st = (((-damping[iter]) * res) * nzS[iter * 6 + tid]) * 0.01f;
            float xi[6];
#pragma unroll
            for (int j = 0; j < 6; j++) xi[j] = __shfl(st, j, 64);
            if (tid == 0) {
                float dT[12];
                se3_exp6(xi, dT);
                float Told[16];
                for (int k = 0; k < 16; k++) Told[k] = Tsh[k];
                float Tn[16];
                compose44(dT, Told, Tn);
                for (int k = 0; k < 16; k++) Tsh[k] = Tn[k];
            }
        }
        __syncthreads();
    }
}

__global__ __launch_bounds__(512) void evolve_kernel_gram(
    const float* __restrict__ T_pred, const float* __restrict__ geo,
    const float* __restrict__ Kmat,
    const float* __restrict__ G0, const float* __restrict__ G1, const float* __restrict__ G2,
    float* __restrict__ Tws, float* __restrict__ out,
    uint32_t hk0, uint32_t hk1, IterKeys iks) {
    const int bm = blockIdx.x;
    // XCD swizzle: b = bm%8 keeps one batch's G slice on one XCD's L2.
    const int b = bm & 7;
    const int m = bm >> 3;
    const int tid = threadIdx.x;

    __shared__ float Tsh[16];
    __shared__ float geoS[NPTS * 3];
    __shared__ float red[8];
    __shared__ float nzS[54];
    __shared__ float dampS[9];

    for (int i = tid; i < NPTS * 3; i += 512) geoS[i] = geo[b * NPTS * 3 + i];

    // hoist all 9x6 noise draws (bitwise-identical values) off the LM loop
    if (tid < 54) {
        int it9 = tid / 6, jj = tid % 6;
        uint32_t fi = (uint32_t)((b * NM + m) * 6 + jj);
        nzS[tid] = jax_normal(iks.k0[it9], iks.k1[it9], fi, 3456u);
    }
    if (tid >= 54 && tid < 63) dampS[tid - 54] = iks.damping[tid - 54];

    if (tid == 64) {
        float P[16];
        for (int k = 0; k < 16; k++) P[k] = T_pred[b * 16 + k];
        float Tn[16];
        make_hypothesis(m, P, hk0, hk1, Tn);
        for (int k = 0; k < 16; k++) Tsh[k] = Tn[k];
    }
    __syncthreads();

    float K00 = Kmat[b * 9 + 0], K02 = Kmat[b * 9 + 2];
    float K11 = Kmat[b * 9 + 4], K12 = Kmat[b * 9 + 5];

    run_level_gram<48, 64>(G0 + (size_t)b * 48 * 64 * GP,
                           K00 * 0.25f, K11 * 0.25f, K02 * 0.25f, K12 * 0.25f,
                           geoS, Tsh, red, nzS, dampS, out, b, m, 0, 2);
    run_level_gram<96, 128>(G1 + (size_t)b * 96 * 128 * GP,
                            K00 * 0.5f, K11 * 0.5f, K02 * 0.5f, K12 * 0.5f,
                            geoS, Tsh, red, nzS, dampS, out, b, m, 2, 3);
    run_level_gram<192, 256>(G2 + (size_t)b * 192 * 256 * GP,
                             K00, K11, K02, K12,
                             geoS, Tsh, red, nzS, dampS, out, b, m, 5, 4);

    if (tid < 16) Tws[(size_t)(b * NM16 + m) * 16 + tid] = Tsh[tid];
}

// ---------------- Fallback (NCHW gather, proven-correct) ----------------
template <int C, int H, int W>
__device__ void run_level_nchw(const float* __restrict__ qb, const float* __restrict__ rb,
                               const float* __restrict__ ub,
                               float fx, float fy, float cx, float cy,
                               const float* geoS, float* Tsh, float* red, float* resS,
                               float* stepS, float* out, int b, int m,
                               const IterKeys& iks, int firstIter, int niter) {
    const int tid = threadIdx.x;
    const int HW = H * W;
    for (int it = 0; it < niter; it++) {
        const int iter = firstIter + it;
        float acc = 0.0f;
        if (tid < NPTS) {
            float px = geoS[tid * 3], py = geoS[tid * 3 + 1], pz = geoS[tid * 3 + 2];
            float X = Tsh[0] * px + Tsh[1] * py + Tsh[2]  * pz + Tsh[3];
            float Y = Tsh[4] * px + Tsh[5] * py + Tsh[6]  * pz + Tsh[7];
            float Z = Tsh[8] * px + Tsh[9] * py + Tsh[10] * pz + Tsh[11];
            float z = fmaxf(Z, 1e-6f);
            float uu = fx * (X / z) + cx;
            float vv = fy * (Y / z) + cy;
            float gx = 2.0f * uu / (float)(W - 1) - 1.0f;
            float gy = 2.0f * vv / (float)(H - 1) - 1.0f;
            float x = fminf(fmaxf(((gx + 1.0f) * (float)W - 1.0f) * 0.5f, 0.0f), (float)(W - 1));
            float y = fminf(fmaxf(((gy + 1.0f) * (float)H - 1.0f) * 0.5f, 0.0f), (float)(H - 1));
            float x0f = floorf(x), y0f = floorf(y);
            float x1f = fminf(x0f + 1.0f, (float)(W - 1));
            float y1f = fminf(y0f + 1.0f, (float)(H - 1));
            float wx = x - x0f, wy = y - y0f;
            int x0i = (int)x0f, x1i = (int)x1f, y0i = (int)y0f, y1i = (int)y1f;
            int i00 = y0i * W + x0i, i01 = y0i * W + x1i;
            int i10 = y1i * W + x0i, i11 = y1i * W + x1i;
            float w00 = (1.0f - wx) * (1.0f - wy), w01 = wx * (1.0f - wy);
            float w10 = (1.0f - wx) * wy,          w11 = wx * wy;
            float uval = ub[i00] * w00 + ub[i01] * w01 + ub[i10] * w10 + ub[i11] * w11;
            const float* qp = qb;
            const float* rp = rb;
#pragma unroll 4
            for (int c = 0; c < C; c++) {
                float qv = qp[i00] * w00 + qp[i01] * w01 + qp[i10] * w10 + qp[i11] * w11;
                float rv = rp[i00] * w00 + rp[i01] * w01 + rp[i10] * w10 + rp[i11] * w11;
                float d = qv - rv;
                acc += uval * (d * d);
                qp += HW; rp += HW;
            }
        }
        float v = acc;
        for (int off = 32; off > 0; off >>= 1) v += __shfl_down(v, off, 64);
        if ((tid & 63) == 0) red[tid >> 6] = v;
        __syncthreads();
        if (tid == 0) {
            float s = 0.0f;
            for (int w = 0; w < 8; w++) s += red[w];
            float res = s / 500.0f;
            *resS = res;
            if (iter == 8) out[128 + b * NM + m] = res;
        }
        __syncthreads();
        if (tid < 6) {
            uint32_t fi = (uint32_t)((b * NM + m) * 6 + tid);
            float nz = jax_normal(iks.k0[iter], iks.k1[iter], fi, 3456u);
            stepS[tid] = (((-iks.damping[iter]) * (*resS)) * nz) * 0.01f;
        }
        __syncthreads();
        if (tid == 0) {
            float xi[6];
            for (int j = 0; j < 6; j++) xi[j] = stepS[j];
            float dT[12];
            se3_exp6(xi, dT);
            float Told[16];
            for (int k = 0; k < 16; k++) Told[k] = Tsh[k];
            float Tn[16];
            compose44(dT, Told, Tn);
            for (int k = 0; k < 16; k++) Tsh[k] = Tn[k];
        }
        __syncthreads();
    }
}

__global__ __launch_bounds__(512) void evolve_kernel_nchw(
    const float* __restrict__ T_pred, const float* __restrict__ geo,
    const float* __restrict__ Kmat,
    const float* __restrict__ q0, const float* __restrict__ q1, const float* __restrict__ q2,
    const float* __restrict__ r0, const float* __restrict__ r1, const float* __restrict__ r2,
    const float* __restrict__ u0, const float* __restrict__ u1, const float* __restrict__ u2,
    float* __restrict__ Tws, float* __restrict__ out,
    uint32_t hk0, uint32_t hk1, IterKeys iks) {
    const int bm = blockIdx.x;
    const int b = bm >> 4;
    const int m = bm & 15;
    const int tid = threadIdx.x;

    __shared__ float Tsh[16];
    __shared__ float geoS[NPTS * 3];
    __shared__ float red[8];
    __shared__ float resS;
    __shared__ float stepS[6];

    for (int i = tid; i < NPTS * 3; i += 512) geoS[i] = geo[b * NPTS * 3 + i];

    if (tid == 0) {
        float P[16];
        for (int k = 0; k < 16; k++) P[k] = T_pred[b * 16 + k];
        float Tn[16];
        make_hypothesis(m, P, hk0, hk1, Tn);
        for (int k = 0; k < 16; k++) Tsh[k] = Tn[k];
    }
    __syncthreads();

    float K00 = Kmat[b * 9 + 0], K02 = Kmat[b * 9 + 2];
    float K11 = Kmat[b * 9 + 4], K12 = Kmat[b * 9 + 5];

    run_level_nchw<128, 48, 64>(q0 + (size_t)b * 128 * 48 * 64, r0 + (size_t)b * 128 * 48 * 64,
                                u0 + (size_t)b * 48 * 64,
                                K00 * 0.25f, K11 * 0.25f, K02 * 0.25f, K12 * 0.25f,
                                geoS, Tsh, red, &resS, stepS, out, b, m, iks, 0, 2);
    run_level_nchw<64, 96, 128>(q1 + (size_t)b * 64 * 96 * 128, r1 + (size_t)b * 64 * 96 * 128,
                                u1 + (size_t)b * 96 * 128,
                                K00 * 0.5f, K11 * 0.5f, K02 * 0.5f, K12 * 0.5f,
                                geoS, Tsh, red, &resS, stepS, out, b, m, iks, 2, 3);
    run_level_nchw<32, 192, 256>(q2 + (size_t)b * 32 * 192 * 256, r2 + (size_t)b * 32 * 192 * 256,
                                 u2 + (size_t)b * 192 * 256,
                                 K00, K11, K02, K12,
                                 geoS, Tsh, red, &resS, stepS, out, b, m, iks, 5, 4);

    if (tid < 16) Tws[(size_t)bm * 16 + tid] = Tsh[tid];
}

// ---------------- Kernel 2: geodesic prior + argmin + T_best (f64 path) ----------------
__global__ __launch_bounds__(192) void finalize_kernel(
    const float* __restrict__ T_pred, const float* __restrict__ Tws,
    float* __restrict__ out, uint32_t hk0, uint32_t hk1) {
    const int b = blockIdx.x;
    const int tid = threadIdx.x;
    __shared__ double Pm[16];
    __shared__ double inv[12];
    __shared__ double totals[NM];
    __shared__ int bestm_sh;

    if (tid < 16) Pm[tid] = (double)T_pred[b * 16 + tid];
    __syncthreads();
    if (tid == 0) {
        for (int k = 0; k < 3; k++)
            for (int j = 0; j < 3; j++) inv[k * 4 + j] = Pm[j * 4 + k];
        for (int k = 0; k < 3; k++)
            inv[k * 4 + 3] = -(Pm[0 * 4 + k] * Pm[3] + Pm[1 * 4 + k] * Pm[7] + Pm[2 * 4 + k] * Pm[11]);
    }
    __syncthreads();

    double Tc[16];
    if (tid < NM) {
        double cost;
        if (tid < NM16) {
            for (int k = 0; k < 16; k++) Tc[k] = (double)Tws[(size_t)(b * NM16 + tid) * 16 + k];
            cost = (double)out[128 + b * NM + tid];
        } else {
            make_hypothesis_d(tid, Pm, hk0, hk1, Tc);
            cost = 0.0;
            out[128 + b * NM + tid] = 0.0f;
        }
        double Tr[12];
        for (int i = 0; i < 3; i++)
            for (int j = 0; j < 4; j++)
                Tr[i * 4 + j] = Tc[i * 4 + 0] * inv[0 + j] + Tc[i * 4 + 1] * inv[4 + j] +
                                Tc[i * 4 + 2] * inv[8 + j] + ((j == 3) ? Tc[i * 4 + 3] : 0.0);
        double cos_a = (Tr[0] + Tr[5] + Tr[10] - 1.0) * 0.5;
        cos_a = fmin(fmax(cos_a, -1.0 + 1e-7), 1.0 - 1e-7);
        double theta = acos(cos_a);
        double th = fmax(theta, 1e-8);
        double s2 = 2.0 * fmax(sin(th), 1e-8);
        double w0 = (Tr[2 * 4 + 1] - Tr[1 * 4 + 2]) / s2 * th;
        double w1 = (Tr[0 * 4 + 2] - Tr[2 * 4 + 0]) / s2 * th;
        double w2 = (Tr[1 * 4 + 0] - Tr[0 * 4 + 1]) / s2 * th;
        double t0 = Tr[3], t1 = Tr[7], t2 = Tr[11];
        double geod = sqrt(t0 * t0 + t1 * t1 + t2 * t2 + w0 * w0 + w1 * w1 + w2 * w2);
        totals[tid] = cost + geod;
    }
    __syncthreads();
    if (tid == 0) {
        int best = 0;
        double bv = totals[0];
        for (int mm = 1; mm < NM; mm++) {
            if (totals[mm] < bv) { bv = totals[mm]; best = mm; }
        }
        bestm_sh = best;
    }
    __syncthreads();
    if (tid == bestm_sh) {
        for (int k = 0; k < 16; k++) out[b * 16 + k] = (float)Tc[k];
    }
}

extern "C" void kernel_launch(void* const* d_in, const int* in_sizes, int n_in,
                              void* d_out, int out_size, void* d_ws, size_t ws_size,
                              hipStream_t stream) {
    (void)in_sizes; (void)n_in; (void)out_size;
    const float* T_pred = (const float*)d_in[0];
    const float* geo    = (const float*)d_in[1];
    const float* K      = (const float*)d_in[2];
    const float* q0 = (const float*)d_in[3];
    const float* q1 = (const float*)d_in[4];
    const float* q2 = (const float*)d_in[5];
    const float* r0 = (const float*)d_in[6];
    const float* r1 = (const float*)d_in[7];
    const float* r2 = (const float*)d_in[8];
    const float* u0 = (const float*)d_in[9];
    const float* u1 = (const float*)d_in[10];
    const float* u2 = (const float*)d_in[11];
    float* out = (float*)d_out;   // [0:128] T_best (8,4,4); [128:1280] costs (8,144)

    // workspace: Tws (2048 f) | G0 | G1 | G2   (GP floats per pixel)
    float* Tws = (float*)d_ws;
    const size_t nG0 = (size_t)NB * 48 * 64 * GP;     //   393,216
    const size_t nG1 = (size_t)NB * 96 * 128 * GP;    // 1,572,864
    const size_t nG2 = (size_t)NB * 192 * 256 * GP;   // 6,291,456
    float* G0 = Tws + 2048;
    float* G1 = G0 + nG0;
    float* G2 = G1 + nG1;
    const size_t need = (2048 + nG0 + nG1 + nG2) * sizeof(float);   // ~33 MB

    // host-side key derivation (pure integer math; graph-capture safe)
    uint32_t hk0, hk1;
    threefry2x32(0u, 42u, 0u, 0u, hk0, hk1);  // fold_in(key(42), 0)
    IterKeys iks;
    const int seeds[9] = {100, 101, 110, 111, 112, 120, 121, 122, 123};
    const float damp[9] = {0.001f, 0.001f, 0.0005f, 0.0005f, 0.0005f,
                           0.00025f, 0.00025f, 0.00025f, 0.00025f};
    for (int i = 0; i < 9; i++) {
        threefry2x32(0u, 42u, 0u, (uint32_t)seeds[i], iks.k0[i], iks.k1[i]);
        iks.damping[i] = damp[i];
    }

    if (ws_size >= need) {
        gram_fused_kernel<<<dim3(SBLKT), dim3(256), 0, stream>>>(
            q0, r0, u0, G0, q1, r1, u1, G1, q2, r2, u2, G2);
        evolve_kernel_gram<<<dim3(NB * NM16), dim3(512), 0, stream>>>(
            T_pred, geo, K, G0, G1, G2, Tws, out, hk0, hk1, iks);
    } else {
        evolve_kernel_nchw<<<dim3(NB * NM16), dim3(512), 0, stream>>>(
            T_pred, geo, K, q0, q1, q2, r0, r1, r2, u0, u1, u2, Tws, out, hk0, hk1, iks);
    }
    finalize_kernel<<<dim3(NB), dim3(192), 0, stream>>>(T_pred, Tws, out, hk0, hk1);
}

// Round 5
// 242.355 us; speedup vs baseline: 1.0477x; 1.0477x over previous
//
#include <hip/hip_runtime.h>
#include <stdint.h>
#include <math.h>

#define JAX_PARTITIONABLE 1

#define NB 8
#define NM 144
#define NM16 16
#define NPTS 500
#define GP 16   // floats per pixel record: 10 Gram + 4 u-taps + 2 pad = one 64B line

typedef float v4f __attribute__((ext_vector_type(4)));

// Non-temporal 16B load: values bitwise-identical to a plain load; the nt flag
// marks the line evict-first so the 178 MB input set stops being served by the
// slow L3-resident path across replays and streams from HBM instead.
__device__ __forceinline__ v4f nt4(const float* p) {
    return __builtin_nontemporal_load((const v4f*)p);
}

// ---------------- Threefry-2x32 (JAX-exact) ----------------
__host__ __device__ __forceinline__ uint32_t rotl32(uint32_t x, int r) {
    return (x << r) | (x >> (32 - r));
}

__host__ __device__ inline void threefry2x32(uint32_t k0, uint32_t k1,
                                             uint32_t x0, uint32_t x1,
                                             uint32_t& o0, uint32_t& o1) {
    uint32_t ks2 = k0 ^ k1 ^ 0x1BD11BDAu;
    x0 += k0; x1 += k1;
    const int RA[4] = {13, 15, 26, 6};
    const int RB[4] = {17, 29, 16, 24};
#define R4(ROT) { x0 += x1; x1 = rotl32(x1, ROT[0]); x1 ^= x0; \
                  x0 += x1; x1 = rotl32(x1, ROT[1]); x1 ^= x0; \
                  x0 += x1; x1 = rotl32(x1, ROT[2]); x1 ^= x0; \
                  x0 += x1; x1 = rotl32(x1, ROT[3]); x1 ^= x0; }
    R4(RA); x0 += k1;  x1 += ks2 + 1u;
    R4(RB); x0 += ks2; x1 += k0 + 2u;
    R4(RA); x0 += k0;  x1 += k1 + 3u;
    R4(RB); x0 += k1;  x1 += ks2 + 4u;
    R4(RA); x0 += ks2; x1 += k0 + 5u;
#undef R4
    o0 = x0; o1 = x1;
}

// XLA f32 erf_inv (Giles polynomial pair)
__device__ __forceinline__ float erfinv32(float x) {
    float w = -log1pf(-x * x);
    float p;
    if (w < 5.0f) {
        w = w - 2.5f;
        p = 2.81022636e-08f;
        p = fmaf(p, w, 3.43273939e-07f);
        p = fmaf(p, w, -3.5233877e-06f);
        p = fmaf(p, w, -4.39150654e-06f);
        p = fmaf(p, w, 0.00021858087f);
        p = fmaf(p, w, -0.00125372503f);
        p = fmaf(p, w, -0.00417768164f);
        p = fmaf(p, w, 0.246640727f);
        p = fmaf(p, w, 1.50140941f);
    } else {
        w = sqrtf(w) - 3.0f;
        p = -0.000200214257f;
        p = fmaf(p, w, 0.000100950558f);
        p = fmaf(p, w, 0.00134934322f);
        p = fmaf(p, w, -0.00367342844f);
        p = fmaf(p, w, 0.00573950773f);
        p = fmaf(p, w, -0.0076224613f);
        p = fmaf(p, w, 0.00943887047f);
        p = fmaf(p, w, 1.00167406f);
        p = fmaf(p, w, 2.83297682f);
    }
    return p * x;
}

// jax.random.normal element at flat index idx (partitionable: bits = o0^o1).
__device__ __forceinline__ float jax_normal(uint32_t k0, uint32_t k1,
                                            uint32_t idx, uint32_t half) {
    uint32_t o0, o1, bits;
#if JAX_PARTITIONABLE
    threefry2x32(k0, k1, 0u, idx, o0, o1);
    bits = o0 ^ o1;
#else
    if (idx < half) { threefry2x32(k0, k1, idx, idx + half, o0, o1); bits = o0; }
    else            { threefry2x32(k0, k1, idx - half, idx, o0, o1); bits = o1; }
#endif
    uint32_t fb = (bits >> 9) | 0x3F800000u;
    float f = __uint_as_float(fb) - 1.0f;           // [0,1)
    const float lo = -0.99999994f;                  // nextafter(-1,0) f32
    float u = f * (1.0f - lo) + lo;                 // (1.0f - lo) == 2.0f
    u = fmaxf(lo, u);
    return 1.4142135623730951f * erfinv32(u);
}

// ---------------- SE(3) helpers, f32 (evolve path) ----------------
__device__ inline void se3_exp6(const float xi[6], float T[12]) {
    float tx = xi[0], ty = xi[1], tz = xi[2];
    float wx = xi[3], wy = xi[4], wz = xi[5];
    float nrm = sqrtf(wx * wx + wy * wy + wz * wz);
    float theta = fmaxf(nrm, 1e-8f);
    float kx = wx / theta, ky = wy / theta, kz = wz / theta;
    float K[9] = {0.0f, -kz, ky, kz, 0.0f, -kx, -ky, kx, 0.0f};
    float st = sinf(theta);
    float ct = 1.0f - cosf(theta);
    float KK[9];
    for (int i = 0; i < 3; i++)
        for (int j = 0; j < 3; j++)
            KK[i * 3 + j] = K[i * 3 + 0] * K[0 + j] + K[i * 3 + 1] * K[3 + j] + K[i * 3 + 2] * K[6 + j];
    float a = ct / theta;
    float bb = 1.0f - st / theta;
    float R[9], V[9];
    for (int i = 0; i < 3; i++)
        for (int j = 0; j < 3; j++) {
            float e = (i == j) ? 1.0f : 0.0f;
            R[i * 3 + j] = e + st * K[i * 3 + j] + ct * KK[i * 3 + j];
            V[i * 3 + j] = e + a * K[i * 3 + j] + bb * KK[i * 3 + j];
        }
    float t0 = V[0] * tx + V[1] * ty + V[2] * tz;
    float t1 = V[3] * tx + V[4] * ty + V[5] * tz;
    float t2 = V[6] * tx + V[7] * ty + V[8] * tz;
    T[0] = R[0]; T[1] = R[1]; T[2] = R[2];  T[3] = t0;
    T[4] = R[3]; T[5] = R[4]; T[6] = R[5];  T[7] = t1;
    T[8] = R[6]; T[9] = R[7]; T[10] = R[8]; T[11] = t2;
}

__device__ inline void compose44(const float dT[12], const float P[16], float Tn[16]) {
    for (int i = 0; i < 3; i++)
        for (int j = 0; j < 4; j++)
            Tn[i * 4 + j] = dT[i * 4 + 0] * P[0 + j] + dT[i * 4 + 1] * P[4 + j] +
                            dT[i * 4 + 2] * P[8 + j] + dT[i * 4 + 3] * P[12 + j];
    Tn[12] = 0.0f; Tn[13] = 0.0f; Tn[14] = 0.0f; Tn[15] = 1.0f;
}

__device__ inline void make_hypothesis(int m, const float* P, uint32_t hk0, uint32_t hk1,
                                       float Tn[16]) {
    float tn[3];
    for (int c = 0; c < 3; c++)
        tn[c] = jax_normal(hk0, hk1, (uint32_t)(m * 3 + c), 216u);
    int gi = m / 12, gj = m % 12;
    const float d2r = (float)(M_PI / 180.0);
    float xi[6] = {tn[0], tn[1], tn[2], 0.0f,
                   (float)(2 * gi - 11) * d2r, (float)(2 * gj - 11) * d2r};
    float dT[12];
    se3_exp6(xi, dT);
    compose44(dT, P, Tn);
}

// ---------------- SE(3) helpers, f64 (finalize path) ----------------
__device__ inline void se3_exp6d(const double xi[6], double T[12]) {
    double tx = xi[0], ty = xi[1], tz = xi[2];
    double wx = xi[3], wy = xi[4], wz = xi[5];
    double nrm = sqrt(wx * wx + wy * wy + wz * wz);
    double theta = fmax(nrm, 1e-8);
    double kx = wx / theta, ky = wy / theta, kz = wz / theta;
    double K[9] = {0.0, -kz, ky, kz, 0.0, -kx, -ky, kx, 0.0};
    double st = sin(theta);
    double ct = 1.0 - cos(theta);
    double KK[9];
    for (int i = 0; i < 3; i++)
        for (int j = 0; j < 3; j++)
            KK[i * 3 + j] = K[i * 3 + 0] * K[0 + j] + K[i * 3 + 1] * K[3 + j] + K[i * 3 + 2] * K[6 + j];
    double a = ct / theta;
    double bb = 1.0 - st / theta;
    double R[9], V[9];
    for (int i = 0; i < 3; i++)
        for (int j = 0; j < 3; j++) {
            double e = (i == j) ? 1.0 : 0.0;
            R[i * 3 + j] = e + st * K[i * 3 + j] + ct * KK[i * 3 + j];
            V[i * 3 + j] = e + a * K[i * 3 + j] + bb * KK[i * 3 + j];
        }
    double t0 = V[0] * tx + V[1] * ty + V[2] * tz;
    double t1 = V[3] * tx + V[4] * ty + V[5] * tz;
    double t2 = V[6] * tx + V[7] * ty + V[8] * tz;
    T[0] = R[0]; T[1] = R[1]; T[2] = R[2];  T[3] = t0;
    T[4] = R[3]; T[5] = R[4]; T[6] = R[5];  T[7] = t1;
    T[8] = R[6]; T[9] = R[7]; T[10] = R[8]; T[11] = t2;
}

__device__ inline void compose44d(const double dT[12], const double P[16], double Tn[16]) {
    for (int i = 0; i < 3; i++)
        for (int j = 0; j < 4; j++)
            Tn[i * 4 + j] = dT[i * 4 + 0] * P[0 + j] + dT[i * 4 + 1] * P[4 + j] +
                            dT[i * 4 + 2] * P[8 + j] + dT[i * 4 + 3] * P[12 + j];
    Tn[12] = 0.0; Tn[13] = 0.0; Tn[14] = 0.0; Tn[15] = 1.0;
}

__device__ inline void make_hypothesis_d(int m, const double* P, uint32_t hk0, uint32_t hk1,
                                         double Tn[16]) {
    float tn[3];
    for (int c = 0; c < 3; c++)
        tn[c] = jax_normal(hk0, hk1, (uint32_t)(m * 3 + c), 216u);
    int gi = m / 12, gj = m % 12;
    const float d2r = (float)(M_PI / 180.0);
    float pf = (float)(2 * gi - 11) * d2r;
    float yf = (float)(2 * gj - 11) * d2r;
    double xi[6] = {(double)tn[0], (double)tn[1], (double)tn[2], 0.0,
                    (double)pf, (double)yf};
    double dT[12];
    se3_exp6d(xi, dT);
    compose44d(dT, P, Tn);
}

struct IterKeys { uint32_t k0[9]; uint32_t k1[9]; float damping[9]; };

// ---------------- Fused Gram builder (R1 structure + NT loads) ----------------
// Each thread owns 4 consecutive x-pixels; 4 nt float4 row loads per channel;
// x+4 tap via __shfl_down (rows are 16/32/64 lanes wide -> never straddle a
// wave; row-edge lanes clamp). Barrier-free channel loop; one LDS combine at
// the end for GRP>1. Accumulation order per pixel and group-sum order
// g0+g1+g2+g3 identical to all previous kernels -> bitwise-identical G.
// Record: [M00,M01,M02,M03 | M11,M12,M13,M22 | M23,M33,u00,u01 | u10,u11,0,0]
template <int C, int H, int W, int GRP>
__device__ void gram_body_v(const float* __restrict__ q, const float* __restrict__ r,
                            const float* __restrict__ u, float* __restrict__ G,
                            float* part, int blk) {
    constexpr int HW = H * W;
    constexpr int PT = 256 / GRP;      // pixel-threads per channel-group
    constexpr int PPB = PT * 4;        // pixels per block
    constexpr int TPB = HW / PPB;      // blocks per batch
    constexpr int CPG = C / GRP;       // channels per group (=32 at all levels)
    const int b = blk / TPB;
    const int tile = blk % TPB;
    const int tid = threadIdx.x;
    const int g = tid / PT;
    const int p = tid % PT;
    const int px0 = tile * PPB + p * 4;   // first of this thread's 4 pixels
    const int y = px0 / W;
    const int x0 = px0 - y * W;           // multiple of 4 -> 16B-aligned loads
    const int y1 = (y + 1 < H) ? y + 1 : H - 1;
    const bool edge = (x0 + 4 >= W);      // this thread holds the row-end pixel

    const int rb0 = y * W + x0;
    const int rb1 = y1 * W + x0;
    const float* qp = q + ((size_t)b * C + (size_t)g * CPG) * HW;
    const float* rp = r + ((size_t)b * C + (size_t)g * CPG) * HW;

    float acc[4][10];
#pragma unroll
    for (int j = 0; j < 4; j++)
#pragma unroll
        for (int i = 0; i < 10; i++) acc[j][i] = 0.0f;

#pragma unroll 2
    for (int c = 0; c < CPG; c++) {
        v4f a0 = nt4(qp + rb0);
        v4f a1 = nt4(qp + rb1);
        v4f b0 = nt4(rp + rb0);
        v4f b1 = nt4(rp + rb1);
        qp += HW; rp += HW;
        float e0[5], e1[5];
        e0[0] = a0.x - b0.x; e0[1] = a0.y - b0.y; e0[2] = a0.z - b0.z; e0[3] = a0.w - b0.w;
        e1[0] = a1.x - b1.x; e1[1] = a1.y - b1.y; e1[2] = a1.z - b1.z; e1[3] = a1.w - b1.w;
        // x+4 tap from lane neighbor; rows never straddle a wave (W/4 lanes/row
        // is 16/32/64), and row-edge lanes clamp so the cross-row value is dead.
        float d0n = __shfl_down(e0[0], 1, 64);
        float d1n = __shfl_down(e1[0], 1, 64);
        e0[4] = edge ? e0[3] : d0n;
        e1[4] = edge ? e1[3] : d1n;
#pragma unroll
        for (int j = 0; j < 4; j++) {
            float d00 = e0[j], d01 = e0[j + 1];
            float d10 = e1[j], d11 = e1[j + 1];
            acc[j][0] = fmaf(d00, d00, acc[j][0]);
            acc[j][1] = fmaf(d00, d01, acc[j][1]);
            acc[j][2] = fmaf(d00, d10, acc[j][2]);
            acc[j][3] = fmaf(d00, d11, acc[j][3]);
            acc[j][4] = fmaf(d01, d01, acc[j][4]);
            acc[j][5] = fmaf(d01, d10, acc[j][5]);
            acc[j][6] = fmaf(d01, d11, acc[j][6]);
            acc[j][7] = fmaf(d10, d10, acc[j][7]);
            acc[j][8] = fmaf(d10, d11, acc[j][8]);
            acc[j][9] = fmaf(d11, d11, acc[j][9]);
        }
    }
    if (GRP > 1) {
        if (g > 0) {
            float* pp = part + (size_t)(g - 1) * 40 * PT;
#pragma unroll
            for (int j = 0; j < 4; j++)
#pragma unroll
                for (int i = 0; i < 10; i++)
                    pp[(j * 10 + i) * PT + p] = acc[j][i];   // stride-1 in p
        }
        __syncthreads();
        if (g == 0) {
            for (int gg = 1; gg < GRP; gg++) {
                const float* pp = part + (size_t)(gg - 1) * 40 * PT;
#pragma unroll
                for (int j = 0; j < 4; j++)
#pragma unroll
                    for (int i = 0; i < 10; i++)
                        acc[j][i] += pp[(j * 10 + i) * PT + p];  // order g0+g1+...
            }
        }
    }
    if (g == 0) {   // whole waves (PT is 64/128/256) -> shuffles are wave-uniform
        const float* ub = u + (size_t)b * HW;
        float4 u0 = *(const float4*)(ub + rb0);
        float4 u1 = *(const float4*)(ub + rb1);
        float w0[5], w1[5];
        w0[0] = u0.x; w0[1] = u0.y; w0[2] = u0.z; w0[3] = u0.w;
        w1[0] = u1.x; w1[1] = u1.y; w1[2] = u1.z; w1[3] = u1.w;
        float u0n = __shfl_down(u0.x, 1, 64);
        float u1n = __shfl_down(u1.x, 1, 64);
        w0[4] = edge ? w0[3] : u0n;
        w1[4] = edge ? w1[3] : u1n;
#pragma unroll
        for (int j = 0; j < 4; j++) {
            size_t base = ((size_t)b * HW + px0 + j) * GP;
            float4 g0v = {acc[j][0], acc[j][1], acc[j][2], acc[j][3]};
            float4 g1v = {acc[j][4], acc[j][5], acc[j][6], acc[j][7]};
            float4 g2v = {acc[j][8], acc[j][9], w0[j], w0[j + 1]};
            float4 g3v = {w1[j], w1[j + 1], 0.0f, 0.0f};
            *(float4*)(G + base + 0)  = g0v;
            *(float4*)(G + base + 4)  = g1v;
            *(float4*)(G + base + 8)  = g2v;
            *(float4*)(G + base + 12) = g3v;
        }
    }
}

#define VBLK0 96     // L0: GRP=4, 256 px/blk, 12 tiles x 8 batches
#define VBLK1 192    // L1: GRP=2, 512 px/blk, 24 tiles x 8
#define VBLK2 384    // L2: GRP=1, 1024 px/blk, 48 tiles x 8

__global__ __launch_bounds__(256) void gram_fused_kernel(
    const float* __restrict__ q0, const float* __restrict__ r0, const float* __restrict__ u0,
    float* __restrict__ G0,
    const float* __restrict__ q1, const float* __restrict__ r1, const float* __restrict__ u1,
    float* __restrict__ G1,
    const float* __restrict__ q2, const float* __restrict__ r2, const float* __restrict__ u2,
    float* __restrict__ G2) {
    __shared__ float part[3 * 40 * 64];   // max (GRP-1)*40*PT = 7680 floats (30 KB)
    const int blk = blockIdx.x;
    if (blk < VBLK0)
        gram_body_v<128, 48, 64, 4>(q0, r0, u0, G0, part, blk);
    else if (blk < VBLK0 + VBLK1)
        gram_body_v<64, 96, 128, 2>(q1, r1, u1, G1, part, blk - VBLK0);
    else
        gram_body_v<32, 192, 256, 1>(q2, r2, u2, G2, part, blk - VBLK0 - VBLK1);
}

// ---------------- Kernel 1 (Gram): per-(b,m) full 9-iteration LM ----------------
// Register-T LM loop: every lane keeps T in 12 VGPRs and redundantly computes
// the whole tail (8-sum in the same serial order, step, se3_exp, compose) from
// identical LDS inputs -> deterministic, bitwise-identical T across lanes.
// ONE barrier per iteration; red[] double-buffered by iteration parity (a wave
// can only reach iteration it+2's red write after crossing barrier it+1, which
// is after every wave's iteration-it read -> race-free).
template <int H, int W>
__device__ void run_level_regT(const float* __restrict__ Gb,
                               float fx, float fy, float cx, float cy,
                               const float* geoS, float Treg[12],
                               float (*red)[8],
                               const float* nzS, const float* dampS,
                               float* out, int b, int m, int firstIter, int niter) {
    const int tid = threadIdx.x;
    for (int it = 0; it < niter; it++) {
        const int iter = firstIter + it;
        float acc = 0.0f;
        if (tid < NPTS) {
            float px = geoS[tid * 3], py = geoS[tid * 3 + 1], pz = geoS[tid * 3 + 2];
            float X = Treg[0] * px + Treg[1] * py + Treg[2]  * pz + Treg[3];
            float Y = Treg[4] * px + Treg[5] * py + Treg[6]  * pz + Treg[7];
            float Z = Treg[8] * px + Treg[9] * py + Treg[10] * pz + Treg[11];
            float z = fmaxf(Z, 1e-6f);
            float uu = fx * (X / z) + cx;
            float vv = fy * (Y / z) + cy;
            float gx = 2.0f * uu / (float)(W - 1) - 1.0f;
            float gy = 2.0f * vv / (float)(H - 1) - 1.0f;
            float x = fminf(fmaxf(((gx + 1.0f) * (float)W - 1.0f) * 0.5f, 0.0f), (float)(W - 1));
            float y = fminf(fmaxf(((gy + 1.0f) * (float)H - 1.0f) * 0.5f, 0.0f), (float)(H - 1));
            float x0f = floorf(x), y0f = floorf(y);
            float wx = x - x0f, wy = y - y0f;
            int x0i = (int)x0f, y0i = (int)y0f;
            int i00 = y0i * W + x0i;
            float w00 = (1.0f - wx) * (1.0f - wy), w01 = wx * (1.0f - wy);
            float w10 = (1.0f - wx) * wy,          w11 = wx * wy;
            const float* Gp = Gb + (size_t)i00 * GP;
            float4 g0 = *(const float4*)(Gp + 0);
            float4 g1 = *(const float4*)(Gp + 4);
            float4 g2 = *(const float4*)(Gp + 8);
            float4 g3 = *(const float4*)(Gp + 12);
            float uval = w00 * g2.z + w01 * g2.w + w10 * g3.x + w11 * g3.y;
            float val = w00 * w00 * g0.x + w01 * w01 * g1.x +
                        w10 * w10 * g1.w + w11 * w11 * g2.y +
                        2.0f * (w00 * w01 * g0.y + w00 * w10 * g0.z + w00 * w11 * g0.w +
                                w01 * w10 * g1.y + w01 * w11 * g1.z + w10 * w11 * g2.x);
            acc = uval * val;
        }
        // per-wave reduction (8 waves) -> red[parity][]
        float v = acc;
        for (int off = 32; off > 0; off >>= 1) v += __shfl_down(v, off, 64);
        if ((tid & 63) == 0) red[iter & 1][tid >> 6] = v;
        __syncthreads();
        // every lane finishes the iteration redundantly (identical inputs ->
        // identical results; same serial order as before)
        float s = 0.0f;
        for (int w = 0; w < 8; w++) s += red[iter & 1][w];
        float res = s / 500.0f;
        if (tid == 0 && iter == 8) out[128 + b * NM + m] = res;
        float xi[6];
#pragma unroll
        for (int j = 0; j < 6; j++)
            xi[j] = (((-dampS[iter]) * res) * nzS[iter * 6 + j]) * 0.01f;
        float dT[12];
        se3_exp6(xi, dT);
        float Tn[12];
#pragma unroll
        for (int i = 0; i < 3; i++)
#pragma unroll
            for (int j = 0; j < 4; j++)
                Tn[i * 4 + j] = dT[i * 4 + 0] * Treg[0 + j] + dT[i * 4 + 1] * Treg[4 + j] +
                                dT[i * 4 + 2] * Treg[8 + j] +
                                dT[i * 4 + 3] * ((j == 3) ? 1.0f : 0.0f);
#pragma unroll
        for (int k = 0; k < 12; k++) Treg[k] = Tn[k];
    }
}

__global__ __launch_bounds__(512) void evolve_kernel_gram(
    const float* __restrict__ T_pred, const float* __restrict__ geo,
    const float* __restrict__ Kmat,
    const float* __restrict__ G0, const float* __restrict__ G1, const float* __restrict__ G2,
    float* __restrict__ Tws, float* __restrict__ out,
    uint32_t hk0, uint32_t hk1, IterKeys iks) {
    const int bm = blockIdx.x;
    // XCD swizzle: b = bm%8 keeps one batch's G slice on one XCD's L2.
    const int b = bm & 7;
    const int m = bm >> 3;
    const int tid = threadIdx.x;

    __shared__ float geoS[NPTS * 3];
    __shared__ float red[2][8];
    __shared__ float nzS[54];
    __shared__ float dampS[9];

    for (int i = tid; i < NPTS * 3; i += 512) geoS[i] = geo[b * NPTS * 3 + i];

    // hoist all 9x6 noise draws (bitwise-identical values) off the LM loop
    if (tid < 54) {
        int it9 = tid / 6, jj = tid % 6;
        uint32_t fi = (uint32_t)((b * NM + m) * 6 + jj);
        nzS[tid] = jax_normal(iks.k0[it9], iks.k1[it9], fi, 3456u);
    }
    if (tid >= 54 && tid < 63) dampS[tid - 54] = iks.damping[tid - 54];

    // every lane builds the initial hypothesis redundantly (deterministic)
    float P[16];
    for (int k = 0; k < 16; k++) P[k] = T_pred[b * 16 + k];
    float Tn16[16];
    make_hypothesis(m, P, hk0, hk1, Tn16);
    float Treg[12];
#pragma unroll
    for (int k = 0; k < 12; k++) Treg[k] = Tn16[k];
    __syncthreads();

    float K00 = Kmat[b * 9 + 0], K02 = Kmat[b * 9 + 2];
    float K11 = Kmat[b * 9 + 4], K12 = Kmat[b * 9 + 5];

    run_level_regT<48, 64>(G0 + (size_t)b * 48 * 64 * GP,
                           K00 * 0.25f, K11 * 0.25f, K02 * 0.25f, K12 * 0.25f,
                           geoS, Treg, red, nzS, dampS, out, b, m, 0, 2);
    run_level_regT<96, 128>(G1 + (size_t)b * 96 * 128 * GP,
                            K00 * 0.5f, K11 * 0.5f, K02 * 0.5f, K12 * 0.5f,
                            geoS, Treg, red, nzS, dampS, out, b, m, 2, 3);
    run_level_regT<192, 256>(G2 + (size_t)b * 192 * 256 * GP,
                             K00, K11, K02, K12,
                             geoS, Treg, red, nzS, dampS, out, b, m, 5, 4);

    if (tid == 0) {
        size_t base = (size_t)(b * NM16 + m) * 16;
#pragma unroll
        for (int k = 0; k < 12; k++) Tws[base + k] = Treg[k];
        Tws[base + 12] = 0.0f; Tws[base + 13] = 0.0f;
        Tws[base + 14] = 0.0f; Tws[base + 15] = 1.0f;
    }
}

// ---------------- Fallback (NCHW gather, proven-correct) ----------------
template <int C, int H, int W>
__device__ void run_level_nchw(const float* __restrict__ qb, const float* __restrict__ rb,
                               const float* __restrict__ ub,
                               float fx, float fy, float cx, float cy,
                               const float* geoS, float* Tsh, float* red, float* resS,
                               float* stepS, float* out, int b, int m,
                               const IterKeys& iks, int firstIter, int niter) {
    const int tid = threadIdx.x;
    const int HW = H * W;
    for (int it = 0; it < niter; it++) {
        const int iter = firstIter + it;
        float acc = 0.0f;
        if (tid < NPTS) {
            float px = geoS[tid * 3], py = geoS[tid * 3 + 1], pz = geoS[tid * 3 + 2];
            float X = Tsh[0] * px + Tsh[1] * py + Tsh[2]  * pz + Tsh[3];
            float Y = Tsh[4] * px + Tsh[5] * py + Tsh[6]  * pz + Tsh[7];
            float Z = Tsh[8] * px + Tsh[9] * py + Tsh[10] * pz + Tsh[11];
            float z = fmaxf(Z, 1e-6f);
            float uu = fx * (X / z) + cx;
            float vv = fy * (Y / z) + cy;
            float gx = 2.0f * uu / (float)(W - 1) - 1.0f;
            float gy = 2.0f * vv / (float)(H - 1) - 1.0f;
            float x = fminf(fmaxf(((gx + 1.0f) * (float)W - 1.0f) * 0.5f, 0.0f), (float)(W - 1));
            float y = fminf(fmaxf(((gy + 1.0f) * (float)H - 1.0f) * 0.5f, 0.0f), (float)(H - 1));
            float x0f = floorf(x), y0f = floorf(y);
            float x1f = fminf(x0f + 1.0f, (float)(W - 1));
            float y1f = fminf(y0f + 1.0f, (float)(H - 1));
            float wx = x - x0f, wy = y - y0f;
            int x0i = (int)x0f, x1i = (int)x1f, y0i = (int)y0f, y1i = (int)y1f;
            int i00 = y0i * W + x0i, i01 = y0i * W + x1i;
            int i10 = y1i * W + x0i, i11 = y1i * W + x1i;
            float w00 = (1.0f - wx) * (1.0f - wy), w01 = wx * (1.0f - wy);
            float w10 = (1.0f - wx) * wy,          w11 = wx * wy;
            float uval = ub[i00] * w00 + ub[i01] * w01 + ub[i10] * w10 + ub[i11] * w11;
            const float* qp = qb;
            const float* rp = rb;
#pragma unroll 4
            for (int c = 0; c < C; c++) {
                float qv = qp[i00] * w00 + qp[i01] * w01 + qp[i10] * w10 + qp[i11] * w11;
                float rv = rp[i00] * w00 + rp[i01] * w01 + rp[i10] * w10 + rp[i11] * w11;
                float d = qv - rv;
                acc += uval * (d * d);
                qp += HW; rp += HW;
            }
        }
        float v = acc;
        for (int off = 32; off > 0; off >>= 1) v += __shfl_down(v, off, 64);
        if ((tid & 63) == 0) red[tid >> 6] = v;
        __syncthreads();
        if (tid == 0) {
            float s = 0.0f;
            for (int w = 0; w < 8; w++) s += red[w];
            float res = s / 500.0f;
            *resS = res;
            if (iter == 8) out[128 + b * NM + m] = res;
        }
        __syncthreads();
        if (tid < 6) {
            uint32_t fi = (uint32_t)((b * NM + m) * 6 + tid);
            float nz = jax_normal(iks.k0[iter], iks.k1[iter], fi, 3456u);
            stepS[tid] = (((-iks.damping[iter]) * (*resS)) * nz) * 0.01f;
        }
        __syncthreads();
        if (tid == 0) {
            float xi[6];
            for (int j = 0; j < 6; j++) xi[j] = stepS[j];
            float dT[12];
            se3_exp6(xi, dT);
            float Told[16];
            for (int k = 0; k < 16; k++) Told[k] = Tsh[k];
            float Tn[16];
            compose44(dT, Told, Tn);
            for (int k = 0; k < 16; k++) Tsh[k] = Tn[k];
        }
        __syncthreads();
    }
}

__global__ __launch_bounds__(512) void evolve_kernel_nchw(
    const float* __restrict__ T_pred, const float* __restrict__ geo,
    const float* __restrict__ Kmat,
    const float* __restrict__ q0, const float* __restrict__ q1, const float* __restrict__ q2,
    const float* __restrict__ r0, const float* __restrict__ r1, const float* __restrict__ r2,
    const float* __restrict__ u0, const float* __restrict__ u1, const float* __restrict__ u2,
    float* __restrict__ Tws, float* __restrict__ out,
    uint32_t hk0, uint32_t hk1, IterKeys iks) {
    const int bm = blockIdx.x;
    const int b = bm >> 4;
    const int m = bm & 15;
    const int tid = threadIdx.x;

    __shared__ float Tsh[16];
    __shared__ float geoS[NPTS * 3];
    __shared__ float red[8];
    __shared__ float resS;
    __shared__ float stepS[6];

    for (int i = tid; i < NPTS * 3; i += 512) geoS[i] = geo[b * NPTS * 3 + i];

    if (tid == 0) {
        float P[16];
        for (int k = 0; k < 16; k++) P[k] = T_pred[b * 16 + k];
        float Tn[16];
        make_hypothesis(m, P, hk0, hk1, Tn);
        for (int k = 0; k < 16; k++) Tsh[k] = Tn[k];
    }
    __syncthreads();

    float K00 = Kmat[b * 9 + 0], K02 = Kmat[b * 9 + 2];
    float K11 = Kmat[b * 9 + 4], K12 = Kmat[b * 9 + 5];

    run_level_nchw<128, 48, 64>(q0 + (size_t)b * 128 * 48 * 64, r0 + (size_t)b * 128 * 48 * 64,
                                u0 + (size_t)b * 48 * 64,
                                K00 * 0.25f, K11 * 0.25f, K02 * 0.25f, K12 * 0.25f,
                                geoS, Tsh, red, &resS, stepS, out, b, m, iks, 0, 2);
    run_level_nchw<64, 96, 128>(q1 + (size_t)b * 64 * 96 * 128, r1 + (size_t)b * 64 * 96 * 128,
                                u1 + (size_t)b * 96 * 128,
                                K00 * 0.5f, K11 * 0.5f, K02 * 0.5f, K12 * 0.5f,
                                geoS, Tsh, red, &resS, stepS, out, b, m, iks, 2, 3);
    run_level_nchw<32, 192, 256>(q2 + (size_t)b * 32 * 192 * 256, r2 + (size_t)b * 32 * 192 * 256,
                                 u2 + (size_t)b * 192 * 256,
                                 K00, K11, K02, K12,
                                 geoS, Tsh, red, &resS, stepS, out, b, m, iks, 5, 4);

    if (tid < 16) Tws[(size_t)bm * 16 + tid] = Tsh[tid];
}

// ---------------- Kernel 2: geodesic prior + argmin + T_best (f64 path) ----------------
__global__ __launch_bounds__(192) void finalize_kernel(
    const float* __restrict__ T_pred, const float* __restrict__ Tws,
    float* __restrict__ out, uint32_t hk0, uint32_t hk1) {
    const int b = blockIdx.x;
    const int tid = threadIdx.x;
    __shared__ double Pm[16];
    __shared__ double inv[12];
    __shared__ double totals[NM];
    __shared__ int bestm_sh;

    if (tid < 16) Pm[tid] = (double)T_pred[b * 16 + tid];
    __syncthreads();
    if (tid == 0) {
        for (int k = 0; k < 3; k++)
            for (int j = 0; j < 3; j++) inv[k * 4 + j] = Pm[j * 4 + k];
        for (int k = 0; k < 3; k++)
            inv[k * 4 + 3] = -(Pm[0 * 4 + k] * Pm[3] + Pm[1 * 4 + k] * Pm[7] + Pm[2 * 4 + k] * Pm[11]);
    }
    __syncthreads();

    double Tc[16];
    if (tid < NM) {
        double cost;
        if (tid < NM16) {
            for (int k = 0; k < 16; k++) Tc[k] = (double)Tws[(size_t)(b * NM16 + tid) * 16 + k];
            cost = (double)out[128 + b * NM + tid];
        } else {
            make_hypothesis_d(tid, Pm, hk0, hk1, Tc);
            cost = 0.0;
            out[128 + b * NM + tid] = 0.0f;
        }
        double Tr[12];
        for (int i = 0; i < 3; i++)
            for (int j = 0; j < 4; j++)
                Tr[i * 4 + j] = Tc[i * 4 + 0] * inv[0 + j] + Tc[i * 4 + 1] * inv[4 + j] +
                                Tc[i * 4 + 2] * inv[8 + j] + ((j == 3) ? Tc[i * 4 + 3] : 0.0);
        double cos_a = (Tr[0] + Tr[5] + Tr[10] - 1.0) * 0.5;
        cos_a = fmin(fmax(cos_a, -1.0 + 1e-7), 1.0 - 1e-7);
        double theta = acos(cos_a);
        double th = fmax(theta, 1e-8);
        double s2 = 2.0 * fmax(sin(th), 1e-8);
        double w0 = (Tr[2 * 4 + 1] - Tr[1 * 4 + 2]) / s2 * th;
        double w1 = (Tr[0 * 4 + 2] - Tr[2 * 4 + 0]) / s2 * th;
        double w2 = (Tr[1 * 4 + 0] - Tr[0 * 4 + 1]) / s2 * th;
        double t0 = Tr[3], t1 = Tr[7], t2 = Tr[11];
        double geod = sqrt(t0 * t0 + t1 * t1 + t2 * t2 + w0 * w0 + w1 * w1 + w2 * w2);
        totals[tid] = cost + geod;
    }
    __syncthreads();
    if (tid == 0) {
        int best = 0;
        double bv = totals[0];
        for (int mm = 1; mm < NM; mm++) {
            if (totals[mm] < bv) { bv = totals[mm]; best = mm; }
        }
        bestm_sh = best;
    }
    __syncthreads();
    if (tid == bestm_sh) {
        for (int k = 0; k < 16; k++) out[b * 16 + k] = (float)Tc[k];
    }
}

extern "C" void kernel_launch(void* const* d_in, const int* in_sizes, int n_in,
                              void* d_out, int out_size, void* d_ws, size_t ws_size,
                              hipStream_t stream) {
    (void)in_sizes; (void)n_in; (void)out_size;
    const float* T_pred = (const float*)d_in[0];
    const float* geo    = (const float*)d_in[1];
    const float* K      = (const float*)d_in[2];
    const float* q0 = (const float*)d_in[3];
    const float* q1 = (const float*)d_in[4];
    const float* q2 = (const float*)d_in[5];
    const float* r0 = (const float*)d_in[6];
    const float* r1 = (const float*)d_in[7];
    const float* r2 = (const float*)d_in[8];
    const float* u0 = (const float*)d_in[9];
    const float* u1 = (const float*)d_in[10];
    const float* u2 = (const float*)d_in[11];
    float* out = (float*)d_out;   // [0:128] T_best (8,4,4); [128:1280] costs (8,144)

    // workspace: Tws (2048 f) | G0 | G1 | G2   (GP floats per pixel)
    float* Tws = (float*)d_ws;
    const size_t nG0 = (size_t)NB * 48 * 64 * GP;     //   393,216
    const size_t nG1 = (size_t)NB * 96 * 128 * GP;    // 1,572,864
    const size_t nG2 = (size_t)NB * 192 * 256 * GP;   // 6,291,456
    float* G0 = Tws + 2048;
    float* G1 = G0 + nG0;
    float* G2 = G1 + nG1;
    const size_t need = (2048 + nG0 + nG1 + nG2) * sizeof(float);   // ~33 MB

    // host-side key derivation (pure integer math; graph-capture safe)
    uint32_t hk0, hk1;
    threefry2x32(0u, 42u, 0u, 0u, hk0, hk1);  // fold_in(key(42), 0)
    IterKeys iks;
    const int seeds[9] = {100, 101, 110, 111, 112, 120, 121, 122, 123};
    const float damp[9] = {0.001f, 0.001f, 0.0005f, 0.0005f, 0.0005f,
                           0.00025f, 0.00025f, 0.00025f, 0.00025f};
    for (int i = 0; i < 9; i++) {
        threefry2x32(0u, 42u, 0u, (uint32_t)seeds[i], iks.k0[i], iks.k1[i]);
        iks.damping[i] = damp[i];
    }

    if (ws_size >= need) {
        gram_fused_kernel<<<dim3(VBLK0 + VBLK1 + VBLK2), dim3(256), 0, stream>>>(
            q0, r0, u0, G0, q1, r1, u1, G1, q2, r2, u2, G2);
        evolve_kernel_gram<<<dim3(NB * NM16), dim3(512), 0, stream>>>(
            T_pred, geo, K, G0, G1, G2, Tws, out, hk0, hk1, iks);
    } else {
        evolve_kernel_nchw<<<dim3(NB * NM16), dim3(512), 0, stream>>>(
            T_pred, geo, K, q0, q1, q2, r0, r1, r2, u0, u1, u2, Tws, out, hk0, hk1, iks);
    }
    finalize_kernel<<<dim3(NB), dim3(192), 0, stream>>>(T_pred, Tws, out, hk0, hk1);
}